// Round 11
// baseline (433.264 us; speedup 1.0000x reference)
//
#include <hip/hip_runtime.h>

#define NN 100000
#define EE 1600000
#define GG 64
#define HH 128
#define BN_EPS 1e-5f

#define CB 782            // coarse buckets = ceil(NN/128), bucket = dst>>7
#define NB 256            // tiles for hist/scatter passes
#define TILE 6250         // EE / NB exactly

typedef unsigned short ushort_t;
typedef __attribute__((ext_vector_type(8))) short bf16x8;
typedef __attribute__((ext_vector_type(4))) float f32x4;

#define MFMA16 __builtin_amdgcn_mfma_f32_16x16x32_bf16

// fragment block size: 128x128 elements = 16384 ushorts (hi), lo follows at +16384
#define WFRAG_LO 16384

// round-to-nearest-even fp32 -> bf16 (finite values)
static __device__ inline ushort_t f2bf(float f) {
    unsigned u = __float_as_uint(f);
    unsigned r = (u + 0x7FFF + ((u >> 16) & 1)) >> 16;
    return (ushort_t)r;
}
static __device__ inline float bf2f(ushort_t b) {
    return __uint_as_float(((unsigned)b) << 16);
}

// ---------------- graph prep: atomic-free two-level counting sort ----------------
// (PROVEN r6 chain. r8's global-atomic scatter alternative: 112us in k_scatter
//  alone from 12x write amplification on random 4B stores. Do not replace.)

__global__ __launch_bounds__(256) void k_hist(const int* __restrict__ ei,
                                              int* __restrict__ histG) {
    __shared__ int h[CB];
    int t = threadIdx.x;
    for (int i = t; i < CB; i += 256) h[i] = 0;
    __syncthreads();
    int e0 = blockIdx.x * TILE;
    for (int i = t; i < TILE; i += 256) {
        int d = ei[EE + e0 + i];
        atomicAdd(&h[d >> 7], 1);
    }
    __syncthreads();
    for (int i = t; i < CB; i += 256) histG[blockIdx.x * CB + i] = h[i];
}

__global__ __launch_bounds__(NB) void k_bscan(int* __restrict__ histG,
                                              int* __restrict__ total) {
    __shared__ int sh[NB];
    int t = threadIdx.x;
    int c = blockIdx.x;
    sh[t] = histG[t * CB + c];
    __syncthreads();
    for (int d = 1; d < NB; d <<= 1) {
        int x = (t >= d) ? sh[t - d] : 0;
        __syncthreads();
        sh[t] += x;
        __syncthreads();
    }
    histG[t * CB + c] = (t > 0) ? sh[t - 1] : 0;
    if (t == NB - 1) total[c] = sh[NB - 1];
}

__global__ __launch_bounds__(1024) void k_cbase(const int* __restrict__ total,
                                                int* __restrict__ cbase) {
    __shared__ int sh[1024];
    int t = threadIdx.x;
    sh[t] = (t < CB) ? total[t] : 0;
    __syncthreads();
    for (int d = 1; d < 1024; d <<= 1) {
        int x = (t >= d) ? sh[t - d] : 0;
        __syncthreads();
        sh[t] += x;
        __syncthreads();
    }
    if (t < CB) cbase[t] = (t > 0) ? sh[t - 1] : 0;
    if (t == CB - 1) cbase[CB] = sh[t];   // == EE
}

__global__ __launch_bounds__(256) void k_cscatter(const int* __restrict__ ei,
                                                  const int* __restrict__ histG,
                                                  const int* __restrict__ cbase,
                                                  int* __restrict__ metaS) {
    __shared__ int base_l[CB];
    __shared__ int cur_l[CB];
    int t = threadIdx.x;
    int b = blockIdx.x;
    for (int i = t; i < CB; i += 256) {
        base_l[i] = cbase[i] + histG[b * CB + i];
        cur_l[i] = 0;
    }
    __syncthreads();
    int e0 = b * TILE;
    for (int i = t; i < TILE; i += 256) {
        int s = ei[e0 + i];
        int d = ei[EE + e0 + i];
        int c = d >> 7;
        int p = base_l[c] + atomicAdd(&cur_l[c], 1);
        metaS[p] = s | ((d & 127) << 17);
    }
}

// pass D: fine histogram, cnt/offs, sorted col; dinv fused at the end
__global__ __launch_bounds__(256) void k_fine(const int* __restrict__ metaS,
                                              const int* __restrict__ cbase,
                                              int* __restrict__ cnt,
                                              int* __restrict__ offs,
                                              int* __restrict__ col,
                                              float* __restrict__ dinv) {
    __shared__ int hist[128];
    __shared__ int scn[128];
    __shared__ int cur[128];
    int t = threadIdx.x;
    int c = blockIdx.x;
    int lo = cbase[c], hi = cbase[c + 1];
    if (t < 128) hist[t] = 0;
    __syncthreads();
    for (int r = lo + t; r < hi; r += 256) atomicAdd(&hist[metaS[r] >> 17], 1);
    __syncthreads();
    if (t < 128) scn[t] = hist[t];
    __syncthreads();
    for (int d = 1; d < 128; d <<= 1) {
        int x = (t >= d && t < 128) ? scn[t - d] : 0;
        __syncthreads();
        if (t < 128) scn[t] += x;
        __syncthreads();
    }
    if (t < 128) {
        int excl = (t > 0) ? scn[t - 1] : 0;
        cur[t] = excl;
        int node = c * 128 + t;
        if (node < NN) {
            cnt[node] = hist[t];
            offs[node] = lo + excl;
            dinv[node] = rsqrtf((float)(hist[t] + 1));   // +1 self loop
        }
    }
    __syncthreads();
    for (int r = lo + t; r < hi; r += 256) {
        int pk = metaS[r];
        int s = pk & 0x1FFFF;
        int idx = atomicAdd(&cur[pk >> 17], 1);
        col[lo + idx] = s;
    }
}

// ---------------- per-graph node counts: binary search on sorted batch ----------------

__global__ __launch_bounds__(64) void k_gcnt(const int* __restrict__ batch,
                                             int* __restrict__ gcnt) {
    int g = threadIdx.x;     // 64 threads, one per graph
    int lo = 0, hi = NN;
    while (lo < hi) { int mid = (lo + hi) >> 1; if (batch[mid] < g) lo = mid + 1; else hi = mid; }
    int a = lo;
    lo = 0; hi = NN;
    int g1 = g + 1;
    while (lo < hi) { int mid = (lo + hi) >> 1; if (batch[mid] < g1) lo = mid + 1; else hi = mid; }
    gcnt[g] = lo - a;
}

// ---------------- weight prep: fp32 W -> hi/lo bf16 MFMA B-fragments ----------------
// layout: frag[((nt*4+kk)*64 + lane)*8 + e] holds W[kk*32 + (lane>>4)*8 + e][nt*16 + (lane&15)]
// hi block = 16384 ushorts (2048 lane-slots x 8); lo block at +WFRAG_LO (=16384)

__global__ __launch_bounds__(256) void k_wprep(const float* __restrict__ W2,
                                               const float* __restrict__ W3,
                                               ushort_t* __restrict__ w2f,
                                               ushort_t* __restrict__ w3f) {
    const float* W = (blockIdx.x & 8) ? W3 : W2;
    ushort_t* o = (blockIdx.x & 8) ? w3f : w2f;
    int tid = ((int)blockIdx.x & 7) * 256 + threadIdx.x;   // 0..2047 = (nt*4+kk)*64 + lane
    int l = tid & 63;
    int kb = ((tid >> 6) & 3) * 32 + (l >> 4) * 8;
    int n = (tid >> 8) * 16 + (l & 15);
    unsigned hp[4], lp[4];
#pragma unroll
    for (int p = 0; p < 4; p++) {
        float v0 = W[(size_t)(kb + 2 * p) * HH + n];
        float v1 = W[(size_t)(kb + 2 * p + 1) * HH + n];
        ushort_t h0 = f2bf(v0), h1 = f2bf(v1);
        ushort_t l0 = f2bf(v0 - bf2f(h0)), l1 = f2bf(v1 - bf2f(h1));
        hp[p] = (unsigned)h0 | ((unsigned)h1 << 16);
        lp[p] = (unsigned)l0 | ((unsigned)l1 << 16);
    }
    *(uint4*)&o[(size_t)tid * 8] = make_uint4(hp[0], hp[1], hp[2], hp[3]);
    *(uint4*)&o[WFRAG_LO + (size_t)tid * 8] = make_uint4(lp[0], lp[1], lp[2], lp[3]);
}

// ---------------- layer 1 aggregate (3-dim) + weight materialize (r6 exact) ----------

__global__ __launch_bounds__(256) void k_aggx(const float* __restrict__ x,
                                              const int* __restrict__ offs,
                                              const int* __restrict__ cnt,
                                              const int* __restrict__ col,
                                              const float* __restrict__ dinv,
                                              float* __restrict__ wgt,
                                              float4* __restrict__ agg) {
    int tid = threadIdx.x;
    int wave = tid >> 6;
    int lane = tid & 63;
    int grp = lane >> 4;
    int l = lane & 15;
    int n = blockIdx.x * 16 + wave * 4 + grp;    // NN % 16 == 0
    float dv = dinv[n];
    int base = offs[n], cn = cnt[n];
    float a0 = 0.f, a1 = 0.f, a2 = 0.f;
    for (int i = l; i < cn; i += 16) {
        int s = col[base + i];
        float w = dinv[s] * dv;
        wgt[base + i] = w;
        a0 += w * x[s * 3 + 0];
        a1 += w * x[s * 3 + 1];
        a2 += w * x[s * 3 + 2];
    }
#pragma unroll
    for (int off = 8; off >= 1; off >>= 1) {
        a0 += __shfl_xor(a0, off, 16);
        a1 += __shfl_xor(a1, off, 16);
        a2 += __shfl_xor(a2, off, 16);
    }
    if (l == 0) {
        float w0 = dv * dv;
        a0 += w0 * x[n * 3 + 0];
        a1 += w0 * x[n * 3 + 1];
        a2 += w0 * x[n * 3 + 2];
        agg[n] = make_float4(a0, a1, a2, 0.f);
    }
}

// ---------------- fused layer1 + layer2: t2 = relu(bn(agg@W1)) @ W2 via MFMA ----------

__global__ __launch_bounds__(256) void k_mml1(const float4* __restrict__ agg,
                                              const float* __restrict__ W1,
                                              const float* __restrict__ b1,
                                              const float* __restrict__ g1,
                                              const float* __restrict__ bb1,
                                              const float* __restrict__ m1,
                                              const float* __restrict__ v1,
                                              const ushort_t* __restrict__ Wf,
                                              ushort_t* __restrict__ outB) {
    __shared__ float4 ag[64];
    __shared__ __align__(16) ushort_t xh[2][64 * HH];
    int tid = threadIdx.x;
    int row0 = blockIdx.x * 64;
    if (tid < 64) {
        int gr = row0 + tid;
        ag[tid] = (gr < NN) ? agg[gr] : make_float4(0.f, 0.f, 0.f, 0.f);
    }
    __syncthreads();
    {
        int c = tid & 127;
        int rh = tid >> 7;
        float w0 = W1[c], w1 = W1[128 + c], w2 = W1[256 + c];
        float sc = g1[c] * rsqrtf(v1[c] + BN_EPS);
        float sh = (b1[c] - m1[c]) * sc + bb1[c];
#pragma unroll
        for (int i = 0; i < 32; i++) {
            int r = 2 * i + rh;
            float4 a = ag[r];
            float t = fmaxf((a.x * w0 + a.y * w1 + a.z * w2) * sc + sh, 0.f);
            ushort_t hi = f2bf(t);
            ushort_t lo = f2bf(t - bf2f(hi));
            int idx = r * HH + (c ^ ((r & 7) << 3));   // XOR swizzle, granule=8 elems
            xh[0][idx] = hi;
            xh[1][idx] = lo;
        }
    }
    __syncthreads();

    int w = tid >> 6, l = tid & 63;
    int r_lo = l & 15, kgrp = l >> 4;
    int row_l = w * 16 + r_lo;                 // local A row 0..63
    f32x4 acc[8];
#pragma unroll
    for (int nt = 0; nt < 8; nt++) acc[nt] = (f32x4){0.f, 0.f, 0.f, 0.f};

#pragma unroll
    for (int kk = 0; kk < 4; kk++) {
        int ke = kk * 32 + kgrp * 8;
        int idx = row_l * HH + (ke ^ ((row_l & 7) << 3));
        bf16x8 ahf = *(const bf16x8*)&xh[0][idx];
        bf16x8 alf = *(const bf16x8*)&xh[1][idx];
#pragma unroll
        for (int nt = 0; nt < 8; nt++) {
            int fo = ((((nt << 2) | kk) << 6) + l) * 8;
            bf16x8 bh = *(const bf16x8*)&Wf[fo];
            bf16x8 bl = *(const bf16x8*)&Wf[WFRAG_LO + fo];
            acc[nt] = MFMA16(ahf, bh, acc[nt], 0, 0, 0);
            acc[nt] = MFMA16(ahf, bl, acc[nt], 0, 0, 0);
            acc[nt] = MFMA16(alf, bh, acc[nt], 0, 0, 0);
        }
    }
    // D layout: col = nt*16 + (lane&15), row = (lane>>4)*4 + q
#pragma unroll
    for (int q = 0; q < 4; q++) {
        int gr = row0 + w * 16 + kgrp * 4 + q;
        if (gr < NN) {
            size_t rb = (size_t)gr * HH + r_lo;
#pragma unroll
            for (int nt = 0; nt < 8; nt++)
                outB[rb + nt * 16] = f2bf(acc[nt][q]);
        }
    }
}

// ---------------- dense 128x128 matmul via MFMA, bf16 in / bf16 out ----------------

__global__ __launch_bounds__(256) void k_mm(const ushort_t* __restrict__ xin,
                                            const ushort_t* __restrict__ Wf,
                                            ushort_t* __restrict__ outB) {
    int tid = threadIdx.x;
    int w = tid >> 6, l = tid & 63;
    int row0 = blockIdx.x * 128 + w * 32;
    int r_lo = l & 15, kgrp = l >> 4;
    f32x4 acc[2][8];
#pragma unroll
    for (int rt = 0; rt < 2; rt++)
#pragma unroll
        for (int nt = 0; nt < 8; nt++) acc[rt][nt] = (f32x4){0.f, 0.f, 0.f, 0.f};

    bf16x8 za = {0, 0, 0, 0, 0, 0, 0, 0};
#pragma unroll
    for (int kk = 0; kk < 4; kk++) {
        int ke = kk * 32 + kgrp * 8;
        int ra0 = row0 + r_lo;
        int ra1 = row0 + 16 + r_lo;
        bf16x8 a0 = (ra0 < NN) ? *(const bf16x8*)&xin[(size_t)ra0 * HH + ke] : za;
        bf16x8 a1 = (ra1 < NN) ? *(const bf16x8*)&xin[(size_t)ra1 * HH + ke] : za;
#pragma unroll
        for (int nt = 0; nt < 8; nt++) {
            int fo = ((((nt << 2) | kk) << 6) + l) * 8;
            bf16x8 bh = *(const bf16x8*)&Wf[fo];
            bf16x8 bl = *(const bf16x8*)&Wf[WFRAG_LO + fo];
            acc[0][nt] = MFMA16(a0, bh, acc[0][nt], 0, 0, 0);
            acc[0][nt] = MFMA16(a0, bl, acc[0][nt], 0, 0, 0);
            acc[1][nt] = MFMA16(a1, bh, acc[1][nt], 0, 0, 0);
            acc[1][nt] = MFMA16(a1, bl, acc[1][nt], 0, 0, 0);
        }
    }
#pragma unroll
    for (int rt = 0; rt < 2; rt++)
#pragma unroll
        for (int q = 0; q < 4; q++) {
            int gr = row0 + rt * 16 + kgrp * 4 + q;
            if (gr < NN) {
                size_t rb = (size_t)gr * HH + r_lo;
#pragma unroll
                for (int nt = 0; nt < 8; nt++)
                    outB[rb + nt * 16] = f2bf(acc[rt][nt][q]);
            }
        }
}

// ---------------- gather-aggregate, CHANNEL-SPLIT (bf16 rows) ------
// Two sequential passes of 64 channels each: working set 12.8MB (vs 25.6MB)
// to raise per-XCD L2 hit rate -> less L2-miss fabric traffic (the measured
// bottleneck: r7 dual-node 2x-MLP and r10 quarter-wave 1/2-loads both neutral,
// so k_agg is miss-traffic-bound, not MLP/issue-bound).
// Inner loop keeps the frozen r0 shape: 8B/lane, branch-free unroll-8 broadcast.
// Per-channel accumulation order identical -> bit-identical output.

__global__ __launch_bounds__(256) void k_aggh(const ushort_t* __restrict__ t,
                                              const int* __restrict__ offs,
                                              const int* __restrict__ cnt,
                                              const int* __restrict__ col,
                                              const float* __restrict__ wgt,
                                              const float* __restrict__ dinv,
                                              const float* __restrict__ bias,
                                              const float* __restrict__ g,
                                              const float* __restrict__ bb,
                                              const float* __restrict__ m,
                                              const float* __restrict__ v,
                                              ushort_t* __restrict__ out,
                                              int pass) {
    int wave = threadIdx.x >> 6;
    int lane = threadIdx.x & 63;
    int grp = lane >> 4;
    int l = lane & 15;
    int d = blockIdx.x * 16 + wave * 4 + grp;    // NN % 16 == 0
    int c0 = (pass << 6) + l * 4;
    float dv = dinv[d];
    float w0 = dv * dv;
    ushort4 selfR = *(const ushort4*)&t[(size_t)d * HH + c0];
    float4 acc;
    acc.x = bf2f(selfR.x) * w0; acc.y = bf2f(selfR.y) * w0;
    acc.z = bf2f(selfR.z) * w0; acc.w = bf2f(selfR.w) * w0;
    int base = offs[d], cn = cnt[d];
    for (int ib = 0; ib < cn; ib += 16) {
        int i = ib + l;
        int s = 0;
        float w = 0.f;
        if (i < cn) {
            s = col[base + i];
            w = wgt[base + i];
        }
        int lim = min(16, cn - ib);
#pragma unroll 8
        for (int j = 0; j < lim; j++) {
            int ss = __shfl(s, j, 16);
            float ww = __shfl(w, j, 16);
            ushort4 tv = *(const ushort4*)&t[(size_t)ss * HH + c0];
            acc.x += ww * bf2f(tv.x);
            acc.y += ww * bf2f(tv.y);
            acc.z += ww * bf2f(tv.z);
            acc.w += ww * bf2f(tv.w);
        }
    }
    float4 gg = *(const float4*)&g[c0];
    float4 vv = *(const float4*)&v[c0];
    float4 mm = *(const float4*)&m[c0];
    float4 bv = *(const float4*)&bb[c0];
    float4 bi = *(const float4*)&bias[c0];
    float sc0 = gg.x * rsqrtf(vv.x + BN_EPS);
    float sc1 = gg.y * rsqrtf(vv.y + BN_EPS);
    float sc2 = gg.z * rsqrtf(vv.z + BN_EPS);
    float sc3 = gg.w * rsqrtf(vv.w + BN_EPS);
    ushort4 o;
    o.x = f2bf(fmaxf(acc.x * sc0 + (bi.x - mm.x) * sc0 + bv.x, 0.f));
    o.y = f2bf(fmaxf(acc.y * sc1 + (bi.y - mm.y) * sc1 + bv.y, 0.f));
    o.z = f2bf(fmaxf(acc.z * sc2 + (bi.z - mm.z) * sc2 + bv.z, 0.f));
    o.w = f2bf(fmaxf(acc.w * sc3 + (bi.w - mm.w) * sc3 + bv.w, 0.f));
    *(ushort4*)&out[(size_t)d * HH + c0] = o;
}

// ---------------- mean pool (bf16 in, fp32 accum) — r0 structure ----------------

#define PBLK 2048
__global__ void k_pool(const ushort_t* __restrict__ h, const int* __restrict__ batch,
                       float* __restrict__ gsum) {
    int c = threadIdx.x;  // 128
    int per = (NN + PBLK - 1) / PBLK;
    int n0 = blockIdx.x * per;
    int n1 = min(NN, n0 + per);
    if (n0 >= NN) return;
    float acc = 0.f;
    int cur = batch[n0];
    for (int n = n0; n < n1; n++) {
        int gr = batch[n];
        if (gr != cur) {
            atomicAdd(&gsum[cur * HH + c], acc);
            acc = 0.f; cur = gr;
        }
        acc += bf2f(h[(size_t)n * HH + c]);
    }
    atomicAdd(&gsum[cur * HH + c], acc);
}

// ---------------- head ----------------

__global__ void k_head(const float* __restrict__ gsum, const int* __restrict__ gcnt,
                       const float* __restrict__ linW, const float* __restrict__ linb,
                       float* __restrict__ out) {
    int t = threadIdx.x;        // 128 = 64 graphs x 2 outputs
    int gr = t >> 1, j = t & 1;
    float inv = 1.0f / fmaxf((float)gcnt[gr], 1.0f);
    float acc = 0.f;
    for (int c = 0; c < HH; c++) acc += gsum[gr * HH + c] * linW[c * 2 + j];
    out[t] = acc * inv + linb[j];
}

// ---------------- host launch ----------------

static inline size_t al256(size_t x) { return (x + 255) & ~(size_t)255; }

extern "C" void kernel_launch(void* const* d_in, const int* in_sizes, int n_in,
                              void* d_out, int out_size, void* d_ws, size_t ws_size,
                              hipStream_t stream) {
    const float* x    = (const float*)d_in[0];
    const int*   ei   = (const int*)d_in[1];
    const int*   batch= (const int*)d_in[2];
    const float* W1   = (const float*)d_in[3];
    const float* b1   = (const float*)d_in[4];
    const float* W2   = (const float*)d_in[5];
    const float* b2   = (const float*)d_in[6];
    const float* W3   = (const float*)d_in[7];
    const float* b3   = (const float*)d_in[8];
    const float* linW = (const float*)d_in[9];
    const float* linb = (const float*)d_in[10];
    const float* bn1g = (const float*)d_in[11];
    const float* bn1b = (const float*)d_in[12];
    const float* bn1m = (const float*)d_in[13];
    const float* bn1v = (const float*)d_in[14];
    const float* bn2g = (const float*)d_in[15];
    const float* bn2b = (const float*)d_in[16];
    const float* bn2m = (const float*)d_in[17];
    const float* bn2v = (const float*)d_in[18];
    const float* bn3g = (const float*)d_in[19];
    const float* bn3b = (const float*)d_in[20];
    const float* bn3m = (const float*)d_in[21];
    const float* bn3v = (const float*)d_in[22];
    float* out = (float*)d_out;

    char* ws = (char*)d_ws;
    size_t off = 0;
    int*    histG  = (int*)(ws + off);    off += al256((size_t)NB * CB * 4);
    int*    total  = (int*)(ws + off);    off += al256((size_t)CB * 4);
    int*    cbase  = (int*)(ws + off);    off += al256((size_t)(CB + 1) * 4);
    int*    cnt    = (int*)(ws + off);    off += al256((size_t)NN * 4);
    int*    offs   = (int*)(ws + off);    off += al256((size_t)NN * 4);
    float*  dinv   = (float*)(ws + off);  off += al256((size_t)NN * 4);
    int*    col    = (int*)(ws + off);    off += al256((size_t)EE * 4);
    float*  wgt    = (float*)(ws + off);  off += al256((size_t)EE * 4);
    ushort_t* w2f  = (ushort_t*)(ws + off); off += al256((size_t)2 * WFRAG_LO * 2);
    ushort_t* w3f  = (ushort_t*)(ws + off); off += al256((size_t)2 * WFRAG_LO * 2);
    float4* agg    = (float4*)(ws + off); off += al256((size_t)NN * 16);
    char*   bufA   = (char*)(ws + off);   off += al256((size_t)NN * HH * 2);
    char*   bufB   = (char*)(ws + off);   off += al256((size_t)NN * HH * 4);
    float*  gsum   = (float*)(ws + off);  off += (size_t)GG * HH * 4;
    int*    gcnt   = (int*)(ws + off);    off += al256((size_t)GG * 4);

    // metaS (coarse-sorted packed edges, 6.4MB) and tB (bf16 t-buffer, 25.6MB)
    // both overlay bufB: metaS fully consumed by k_fine before first t write.
    int* metaS = (int*)bufB;
    ushort_t* tB = (ushort_t*)bufB;
    ushort_t* hB = (ushort_t*)bufA;       // bf16 h buffer (layer-2/3 outputs)

    hipMemsetAsync(gsum, 0, (size_t)GG * HH * 4, stream);

    // weight fragment prep + per-graph counts (independent of sort chain)
    k_wprep<<<16, 256, 0, stream>>>(W2, W3, w2f, w3f);
    k_gcnt<<<1, 64, 0, stream>>>(batch, gcnt);

    // atomic-free counting sort -> CSR (+ dinv fused into k_fine)
    k_hist<<<NB, 256, 0, stream>>>(ei, histG);
    k_bscan<<<CB, NB, 0, stream>>>(histG, total);
    k_cbase<<<1, 1024, 0, stream>>>(total, cbase);
    k_cscatter<<<NB, 256, 0, stream>>>(ei, histG, cbase, metaS);
    k_fine<<<CB, 256, 0, stream>>>(metaS, cbase, cnt, offs, col, dinv);

    // layer 1 aggregate in input space (3-dim) + materialize edge weights
    k_aggx<<<NN / 16, 256, 0, stream>>>(x, offs, cnt, col, dinv, wgt, agg);

    // fused layer1 + layer2 matmul (MFMA): t2 = relu(bn1(agg@W1)) @ W2
    k_mml1<<<(NN + 63) / 64, 256, 0, stream>>>(agg, W1, b1, bn1g, bn1b, bn1m, bn1v,
                                               w2f, tB);
    // layer-2 aggregate: channel-split, two sequential passes (L2 working set 12.8MB)
    k_aggh<<<NN / 16, 256, 0, stream>>>(tB, offs, cnt, col, wgt, dinv,
                                        b2, bn2g, bn2b, bn2m, bn2v, hB, 0);
    k_aggh<<<NN / 16, 256, 0, stream>>>(tB, offs, cnt, col, wgt, dinv,
                                        b2, bn2g, bn2b, bn2m, bn2v, hB, 1);

    // layer 3 (MFMA matmul), then channel-split aggregate, then pool
    k_mm<<<(NN + 127) / 128, 256, 0, stream>>>(hB, w3f, tB);
    k_aggh<<<NN / 16, 256, 0, stream>>>(tB, offs, cnt, col, wgt, dinv,
                                        b3, bn3g, bn3b, bn3m, bn3v, hB, 0);
    k_aggh<<<NN / 16, 256, 0, stream>>>(tB, offs, cnt, col, wgt, dinv,
                                        b3, bn3g, bn3b, bn3m, bn3v, hB, 1);

    // pool + head
    k_pool<<<PBLK, 128, 0, stream>>>(hB, batch, gsum);
    k_head<<<1, 128, 0, stream>>>(gsum, gcnt, linW, linb, out);
}

// Round 12
// 402.331 us; speedup vs baseline: 1.0769x; 1.0769x over previous
//
#include <hip/hip_runtime.h>

#define NN 100000
#define EE 1600000
#define GG 64
#define HH 128
#define BN_EPS 1e-5f

#define CB 782            // coarse buckets = ceil(NN/128), bucket = dst>>7
#define NB 256            // tiles for hist/scatter passes
#define TILE 6250         // EE / NB exactly

typedef unsigned short ushort_t;
typedef __attribute__((ext_vector_type(8))) short bf16x8;
typedef __attribute__((ext_vector_type(4))) float f32x4;

#define MFMA16 __builtin_amdgcn_mfma_f32_16x16x32_bf16

// fragment block size: 128x128 elements = 16384 ushorts (hi), lo follows at +16384
#define WFRAG_LO 16384

// round-to-nearest-even fp32 -> bf16 (finite values)
static __device__ inline ushort_t f2bf(float f) {
    unsigned u = __float_as_uint(f);
    unsigned r = (u + 0x7FFF + ((u >> 16) & 1)) >> 16;
    return (ushort_t)r;
}
static __device__ inline float bf2f(ushort_t b) {
    return __uint_as_float(((unsigned)b) << 16);
}

// ---------------- graph prep: atomic-free two-level counting sort ----------------
// (PROVEN r6 chain. r8's global-atomic scatter alternative: 112us in k_scatter
//  alone from 12x write amplification on random 4B stores. Do not replace.)

__global__ __launch_bounds__(256) void k_hist(const int* __restrict__ ei,
                                              int* __restrict__ histG) {
    __shared__ int h[CB];
    int t = threadIdx.x;
    for (int i = t; i < CB; i += 256) h[i] = 0;
    __syncthreads();
    int e0 = blockIdx.x * TILE;
    for (int i = t; i < TILE; i += 256) {
        int d = ei[EE + e0 + i];
        atomicAdd(&h[d >> 7], 1);
    }
    __syncthreads();
    for (int i = t; i < CB; i += 256) histG[blockIdx.x * CB + i] = h[i];
}

__global__ __launch_bounds__(NB) void k_bscan(int* __restrict__ histG,
                                              int* __restrict__ total) {
    __shared__ int sh[NB];
    int t = threadIdx.x;
    int c = blockIdx.x;
    sh[t] = histG[t * CB + c];
    __syncthreads();
    for (int d = 1; d < NB; d <<= 1) {
        int x = (t >= d) ? sh[t - d] : 0;
        __syncthreads();
        sh[t] += x;
        __syncthreads();
    }
    histG[t * CB + c] = (t > 0) ? sh[t - 1] : 0;
    if (t == NB - 1) total[c] = sh[NB - 1];
}

__global__ __launch_bounds__(1024) void k_cbase(const int* __restrict__ total,
                                                int* __restrict__ cbase) {
    __shared__ int sh[1024];
    int t = threadIdx.x;
    sh[t] = (t < CB) ? total[t] : 0;
    __syncthreads();
    for (int d = 1; d < 1024; d <<= 1) {
        int x = (t >= d) ? sh[t - d] : 0;
        __syncthreads();
        sh[t] += x;
        __syncthreads();
    }
    if (t < CB) cbase[t] = (t > 0) ? sh[t - 1] : 0;
    if (t == CB - 1) cbase[CB] = sh[t];   // == EE
}

__global__ __launch_bounds__(256) void k_cscatter(const int* __restrict__ ei,
                                                  const int* __restrict__ histG,
                                                  const int* __restrict__ cbase,
                                                  int* __restrict__ metaS) {
    __shared__ int base_l[CB];
    __shared__ int cur_l[CB];
    int t = threadIdx.x;
    int b = blockIdx.x;
    for (int i = t; i < CB; i += 256) {
        base_l[i] = cbase[i] + histG[b * CB + i];
        cur_l[i] = 0;
    }
    __syncthreads();
    int e0 = b * TILE;
    for (int i = t; i < TILE; i += 256) {
        int s = ei[e0 + i];
        int d = ei[EE + e0 + i];
        int c = d >> 7;
        int p = base_l[c] + atomicAdd(&cur_l[c], 1);
        metaS[p] = s | ((d & 127) << 17);
    }
}

// pass D: fine histogram, cnt/offs, sorted col; dinv fused at the end
__global__ __launch_bounds__(256) void k_fine(const int* __restrict__ metaS,
                                              const int* __restrict__ cbase,
                                              int* __restrict__ cnt,
                                              int* __restrict__ offs,
                                              int* __restrict__ col,
                                              float* __restrict__ dinv) {
    __shared__ int hist[128];
    __shared__ int scn[128];
    __shared__ int cur[128];
    int t = threadIdx.x;
    int c = blockIdx.x;
    int lo = cbase[c], hi = cbase[c + 1];
    if (t < 128) hist[t] = 0;
    __syncthreads();
    for (int r = lo + t; r < hi; r += 256) atomicAdd(&hist[metaS[r] >> 17], 1);
    __syncthreads();
    if (t < 128) scn[t] = hist[t];
    __syncthreads();
    for (int d = 1; d < 128; d <<= 1) {
        int x = (t >= d && t < 128) ? scn[t - d] : 0;
        __syncthreads();
        if (t < 128) scn[t] += x;
        __syncthreads();
    }
    if (t < 128) {
        int excl = (t > 0) ? scn[t - 1] : 0;
        cur[t] = excl;
        int node = c * 128 + t;
        if (node < NN) {
            cnt[node] = hist[t];
            offs[node] = lo + excl;
            dinv[node] = rsqrtf((float)(hist[t] + 1));   // +1 self loop
        }
    }
    __syncthreads();
    for (int r = lo + t; r < hi; r += 256) {
        int pk = metaS[r];
        int s = pk & 0x1FFFF;
        int idx = atomicAdd(&cur[pk >> 17], 1);
        col[lo + idx] = s;
    }
}

// ---------------- weight prep + per-graph counts (merged: one launch) ----------------
// blocks 0-15: fp32 W -> hi/lo bf16 MFMA B-fragments
//   layout: frag[((nt*4+kk)*64 + lane)*8 + e] = W[kk*32+(lane>>4)*8+e][nt*16+(lane&15)]
//   hi block = 16384 ushorts; lo at +WFRAG_LO
// block 16: binary-search per-graph node counts on sorted batch (64 threads active)

__global__ __launch_bounds__(256) void k_wprep(const float* __restrict__ W2,
                                               const float* __restrict__ W3,
                                               ushort_t* __restrict__ w2f,
                                               ushort_t* __restrict__ w3f,
                                               const int* __restrict__ batch,
                                               int* __restrict__ gcnt) {
    if (blockIdx.x == 16) {
        int g = threadIdx.x;
        if (g < 64) {
            int lo = 0, hi = NN;
            while (lo < hi) { int mid = (lo + hi) >> 1; if (batch[mid] < g) lo = mid + 1; else hi = mid; }
            int a = lo;
            lo = 0; hi = NN;
            int g1 = g + 1;
            while (lo < hi) { int mid = (lo + hi) >> 1; if (batch[mid] < g1) lo = mid + 1; else hi = mid; }
            gcnt[g] = lo - a;
        }
        return;
    }
    const float* W = (blockIdx.x & 8) ? W3 : W2;
    ushort_t* o = (blockIdx.x & 8) ? w3f : w2f;
    int tid = ((int)blockIdx.x & 7) * 256 + threadIdx.x;   // 0..2047 = (nt*4+kk)*64 + lane
    int l = tid & 63;
    int kb = ((tid >> 6) & 3) * 32 + (l >> 4) * 8;
    int n = (tid >> 8) * 16 + (l & 15);
    unsigned hp[4], lp[4];
#pragma unroll
    for (int p = 0; p < 4; p++) {
        float v0 = W[(size_t)(kb + 2 * p) * HH + n];
        float v1 = W[(size_t)(kb + 2 * p + 1) * HH + n];
        ushort_t h0 = f2bf(v0), h1 = f2bf(v1);
        ushort_t l0 = f2bf(v0 - bf2f(h0)), l1 = f2bf(v1 - bf2f(h1));
        hp[p] = (unsigned)h0 | ((unsigned)h1 << 16);
        lp[p] = (unsigned)l0 | ((unsigned)l1 << 16);
    }
    *(uint4*)&o[(size_t)tid * 8] = make_uint4(hp[0], hp[1], hp[2], hp[3]);
    *(uint4*)&o[WFRAG_LO + (size_t)tid * 8] = make_uint4(lp[0], lp[1], lp[2], lp[3]);
}

// ---------------- layer 1 aggregate (3-dim) + weight materialize (r6 exact) ----------

__global__ __launch_bounds__(256) void k_aggx(const float* __restrict__ x,
                                              const int* __restrict__ offs,
                                              const int* __restrict__ cnt,
                                              const int* __restrict__ col,
                                              const float* __restrict__ dinv,
                                              float* __restrict__ wgt,
                                              float4* __restrict__ agg) {
    int tid = threadIdx.x;
    int wave = tid >> 6;
    int lane = tid & 63;
    int grp = lane >> 4;
    int l = lane & 15;
    int n = blockIdx.x * 16 + wave * 4 + grp;    // NN % 16 == 0
    float dv = dinv[n];
    int base = offs[n], cn = cnt[n];
    float a0 = 0.f, a1 = 0.f, a2 = 0.f;
    for (int i = l; i < cn; i += 16) {
        int s = col[base + i];
        float w = dinv[s] * dv;
        wgt[base + i] = w;
        a0 += w * x[s * 3 + 0];
        a1 += w * x[s * 3 + 1];
        a2 += w * x[s * 3 + 2];
    }
#pragma unroll
    for (int off = 8; off >= 1; off >>= 1) {
        a0 += __shfl_xor(a0, off, 16);
        a1 += __shfl_xor(a1, off, 16);
        a2 += __shfl_xor(a2, off, 16);
    }
    if (l == 0) {
        float w0 = dv * dv;
        a0 += w0 * x[n * 3 + 0];
        a1 += w0 * x[n * 3 + 1];
        a2 += w0 * x[n * 3 + 2];
        agg[n] = make_float4(a0, a1, a2, 0.f);
    }
}

// ---------------- fused layer1 + layer2: t2 = relu(bn(agg@W1)) @ W2 via MFMA ----------

__global__ __launch_bounds__(256) void k_mml1(const float4* __restrict__ agg,
                                              const float* __restrict__ W1,
                                              const float* __restrict__ b1,
                                              const float* __restrict__ g1,
                                              const float* __restrict__ bb1,
                                              const float* __restrict__ m1,
                                              const float* __restrict__ v1,
                                              const ushort_t* __restrict__ Wf,
                                              ushort_t* __restrict__ outB) {
    __shared__ float4 ag[64];
    __shared__ __align__(16) ushort_t xh[2][64 * HH];
    int tid = threadIdx.x;
    int row0 = blockIdx.x * 64;
    if (tid < 64) {
        int gr = row0 + tid;
        ag[tid] = (gr < NN) ? agg[gr] : make_float4(0.f, 0.f, 0.f, 0.f);
    }
    __syncthreads();
    {
        int c = tid & 127;
        int rh = tid >> 7;
        float w0 = W1[c], w1 = W1[128 + c], w2 = W1[256 + c];
        float sc = g1[c] * rsqrtf(v1[c] + BN_EPS);
        float sh = (b1[c] - m1[c]) * sc + bb1[c];
#pragma unroll
        for (int i = 0; i < 32; i++) {
            int r = 2 * i + rh;
            float4 a = ag[r];
            float t = fmaxf((a.x * w0 + a.y * w1 + a.z * w2) * sc + sh, 0.f);
            ushort_t hi = f2bf(t);
            ushort_t lo = f2bf(t - bf2f(hi));
            int idx = r * HH + (c ^ ((r & 7) << 3));   // XOR swizzle, granule=8 elems
            xh[0][idx] = hi;
            xh[1][idx] = lo;
        }
    }
    __syncthreads();

    int w = tid >> 6, l = tid & 63;
    int r_lo = l & 15, kgrp = l >> 4;
    int row_l = w * 16 + r_lo;                 // local A row 0..63
    f32x4 acc[8];
#pragma unroll
    for (int nt = 0; nt < 8; nt++) acc[nt] = (f32x4){0.f, 0.f, 0.f, 0.f};

#pragma unroll
    for (int kk = 0; kk < 4; kk++) {
        int ke = kk * 32 + kgrp * 8;
        int idx = row_l * HH + (ke ^ ((row_l & 7) << 3));
        bf16x8 ahf = *(const bf16x8*)&xh[0][idx];
        bf16x8 alf = *(const bf16x8*)&xh[1][idx];
#pragma unroll
        for (int nt = 0; nt < 8; nt++) {
            int fo = ((((nt << 2) | kk) << 6) + l) * 8;
            bf16x8 bh = *(const bf16x8*)&Wf[fo];
            bf16x8 bl = *(const bf16x8*)&Wf[WFRAG_LO + fo];
            acc[nt] = MFMA16(ahf, bh, acc[nt], 0, 0, 0);
            acc[nt] = MFMA16(ahf, bl, acc[nt], 0, 0, 0);
            acc[nt] = MFMA16(alf, bh, acc[nt], 0, 0, 0);
        }
    }
    // D layout: col = nt*16 + (lane&15), row = (lane>>4)*4 + q
#pragma unroll
    for (int q = 0; q < 4; q++) {
        int gr = row0 + w * 16 + kgrp * 4 + q;
        if (gr < NN) {
            size_t rb = (size_t)gr * HH + r_lo;
#pragma unroll
            for (int nt = 0; nt < 8; nt++)
                outB[rb + nt * 16] = f2bf(acc[nt][q]);
        }
    }
}

// ---------------- dense 128x128 matmul via MFMA, bf16 in / bf16 out ----------------

__global__ __launch_bounds__(256) void k_mm(const ushort_t* __restrict__ xin,
                                            const ushort_t* __restrict__ Wf,
                                            ushort_t* __restrict__ outB) {
    int tid = threadIdx.x;
    int w = tid >> 6, l = tid & 63;
    int row0 = blockIdx.x * 128 + w * 32;
    int r_lo = l & 15, kgrp = l >> 4;
    f32x4 acc[2][8];
#pragma unroll
    for (int rt = 0; rt < 2; rt++)
#pragma unroll
        for (int nt = 0; nt < 8; nt++) acc[rt][nt] = (f32x4){0.f, 0.f, 0.f, 0.f};

    bf16x8 za = {0, 0, 0, 0, 0, 0, 0, 0};
#pragma unroll
    for (int kk = 0; kk < 4; kk++) {
        int ke = kk * 32 + kgrp * 8;
        int ra0 = row0 + r_lo;
        int ra1 = row0 + 16 + r_lo;
        bf16x8 a0 = (ra0 < NN) ? *(const bf16x8*)&xin[(size_t)ra0 * HH + ke] : za;
        bf16x8 a1 = (ra1 < NN) ? *(const bf16x8*)&xin[(size_t)ra1 * HH + ke] : za;
#pragma unroll
        for (int nt = 0; nt < 8; nt++) {
            int fo = ((((nt << 2) | kk) << 6) + l) * 8;
            bf16x8 bh = *(const bf16x8*)&Wf[fo];
            bf16x8 bl = *(const bf16x8*)&Wf[WFRAG_LO + fo];
            acc[0][nt] = MFMA16(a0, bh, acc[0][nt], 0, 0, 0);
            acc[0][nt] = MFMA16(a0, bl, acc[0][nt], 0, 0, 0);
            acc[1][nt] = MFMA16(a1, bh, acc[1][nt], 0, 0, 0);
            acc[1][nt] = MFMA16(a1, bl, acc[1][nt], 0, 0, 0);
        }
    }
#pragma unroll
    for (int rt = 0; rt < 2; rt++)
#pragma unroll
        for (int q = 0; q < 4; q++) {
            int gr = row0 + rt * 16 + kgrp * 4 + q;
            if (gr < NN) {
                size_t rb = (size_t)gr * HH + r_lo;
#pragma unroll
                for (int nt = 0; nt < 8; nt++)
                    outB[rb + nt * 16] = f2bf(acc[rt][nt][q]);
            }
        }
}

// ---------------- gather-aggregate, FROZEN r0 structure (76us floor) ------
// Structural limit established r7/r10/r11: bound by L2-miss fill traffic for
// random 256B rows (192MB @ ~316GB/s/XCD); insensitive to MLP (r7), load count
// (r10), and working-set size (r11). Do not restructure.

__global__ __launch_bounds__(256) void k_agg(const ushort_t* __restrict__ t,
                                             const int* __restrict__ offs,
                                             const int* __restrict__ cnt,
                                             const int* __restrict__ col,
                                             const float* __restrict__ wgt,
                                             const float* __restrict__ dinv,
                                             const float* __restrict__ bias,
                                             const float* __restrict__ g,
                                             const float* __restrict__ bb,
                                             const float* __restrict__ m,
                                             const float* __restrict__ v,
                                             ushort_t* __restrict__ out) {
    int wave = threadIdx.x >> 6;
    int lane = threadIdx.x & 63;
    int half = lane >> 5;
    int l = lane & 31;
    int d = blockIdx.x * 8 + wave * 2 + half;    // NN % 8 == 0
    int c0 = l * 4;
    float dv = dinv[d];
    float w0 = dv * dv;
    ushort4 selfR = *(const ushort4*)&t[(size_t)d * HH + c0];
    float4 acc;
    acc.x = bf2f(selfR.x) * w0; acc.y = bf2f(selfR.y) * w0;
    acc.z = bf2f(selfR.z) * w0; acc.w = bf2f(selfR.w) * w0;
    int base = offs[d], cn = cnt[d];
    for (int ib = 0; ib < cn; ib += 32) {
        int i = ib + l;
        int s = 0;
        float w = 0.f;
        if (i < cn) {
            s = col[base + i];
            w = wgt[base + i];
        }
        int lim = min(32, cn - ib);
#pragma unroll 8
        for (int j = 0; j < lim; j++) {
            int ss = __shfl(s, j, 32);
            float ww = __shfl(w, j, 32);
            ushort4 tv = *(const ushort4*)&t[(size_t)ss * HH + c0];
            acc.x += ww * bf2f(tv.x);
            acc.y += ww * bf2f(tv.y);
            acc.z += ww * bf2f(tv.z);
            acc.w += ww * bf2f(tv.w);
        }
    }
    float4 gg = *(const float4*)&g[c0];
    float4 vv = *(const float4*)&v[c0];
    float4 mm = *(const float4*)&m[c0];
    float4 bv = *(const float4*)&bb[c0];
    float4 bi = *(const float4*)&bias[c0];
    float sc0 = gg.x * rsqrtf(vv.x + BN_EPS);
    float sc1 = gg.y * rsqrtf(vv.y + BN_EPS);
    float sc2 = gg.z * rsqrtf(vv.z + BN_EPS);
    float sc3 = gg.w * rsqrtf(vv.w + BN_EPS);
    ushort4 o;
    o.x = f2bf(fmaxf(acc.x * sc0 + (bi.x - mm.x) * sc0 + bv.x, 0.f));
    o.y = f2bf(fmaxf(acc.y * sc1 + (bi.y - mm.y) * sc1 + bv.y, 0.f));
    o.z = f2bf(fmaxf(acc.z * sc2 + (bi.z - mm.z) * sc2 + bv.z, 0.f));
    o.w = f2bf(fmaxf(acc.w * sc3 + (bi.w - mm.w) * sc3 + bv.w, 0.f));
    *(ushort4*)&out[(size_t)d * HH + c0] = o;
}

// ---------------- mean pool (bf16 in, fp32 accum) — exact 32-node chunks ----------------

#define PBLK 3125            // 3125 * 32 == NN exactly
__global__ void k_pool(const ushort_t* __restrict__ h, const int* __restrict__ batch,
                       float* __restrict__ gsum) {
    int c = threadIdx.x;  // 128
    int n0 = blockIdx.x * 32;
    int n1 = n0 + 32;
    float acc = 0.f;
    int cur = batch[n0];
    for (int n = n0; n < n1; n++) {
        int gr = batch[n];
        if (gr != cur) {
            atomicAdd(&gsum[cur * HH + c], acc);
            acc = 0.f; cur = gr;
        }
        acc += bf2f(h[(size_t)n * HH + c]);
    }
    atomicAdd(&gsum[cur * HH + c], acc);
}

// ---------------- head ----------------

__global__ void k_head(const float* __restrict__ gsum, const int* __restrict__ gcnt,
                       const float* __restrict__ linW, const float* __restrict__ linb,
                       float* __restrict__ out) {
    int t = threadIdx.x;        // 128 = 64 graphs x 2 outputs
    int gr = t >> 1, j = t & 1;
    float inv = 1.0f / fmaxf((float)gcnt[gr], 1.0f);
    float acc = 0.f;
    for (int c = 0; c < HH; c++) acc += gsum[gr * HH + c] * linW[c * 2 + j];
    out[t] = acc * inv + linb[j];
}

// ---------------- host launch ----------------

static inline size_t al256(size_t x) { return (x + 255) & ~(size_t)255; }

extern "C" void kernel_launch(void* const* d_in, const int* in_sizes, int n_in,
                              void* d_out, int out_size, void* d_ws, size_t ws_size,
                              hipStream_t stream) {
    const float* x    = (const float*)d_in[0];
    const int*   ei   = (const int*)d_in[1];
    const int*   batch= (const int*)d_in[2];
    const float* W1   = (const float*)d_in[3];
    const float* b1   = (const float*)d_in[4];
    const float* W2   = (const float*)d_in[5];
    const float* b2   = (const float*)d_in[6];
    const float* W3   = (const float*)d_in[7];
    const float* b3   = (const float*)d_in[8];
    const float* linW = (const float*)d_in[9];
    const float* linb = (const float*)d_in[10];
    const float* bn1g = (const float*)d_in[11];
    const float* bn1b = (const float*)d_in[12];
    const float* bn1m = (const float*)d_in[13];
    const float* bn1v = (const float*)d_in[14];
    const float* bn2g = (const float*)d_in[15];
    const float* bn2b = (const float*)d_in[16];
    const float* bn2m = (const float*)d_in[17];
    const float* bn2v = (const float*)d_in[18];
    const float* bn3g = (const float*)d_in[19];
    const float* bn3b = (const float*)d_in[20];
    const float* bn3m = (const float*)d_in[21];
    const float* bn3v = (const float*)d_in[22];
    float* out = (float*)d_out;

    char* ws = (char*)d_ws;
    size_t off = 0;
    int*    histG  = (int*)(ws + off);    off += al256((size_t)NB * CB * 4);
    int*    total  = (int*)(ws + off);    off += al256((size_t)CB * 4);
    int*    cbase  = (int*)(ws + off);    off += al256((size_t)(CB + 1) * 4);
    int*    cnt    = (int*)(ws + off);    off += al256((size_t)NN * 4);
    int*    offs   = (int*)(ws + off);    off += al256((size_t)NN * 4);
    float*  dinv   = (float*)(ws + off);  off += al256((size_t)NN * 4);
    int*    col    = (int*)(ws + off);    off += al256((size_t)EE * 4);
    float*  wgt    = (float*)(ws + off);  off += al256((size_t)EE * 4);
    ushort_t* w2f  = (ushort_t*)(ws + off); off += al256((size_t)2 * WFRAG_LO * 2);
    ushort_t* w3f  = (ushort_t*)(ws + off); off += al256((size_t)2 * WFRAG_LO * 2);
    float4* agg    = (float4*)(ws + off); off += al256((size_t)NN * 16);
    char*   bufA   = (char*)(ws + off);   off += al256((size_t)NN * HH * 2);
    char*   bufB   = (char*)(ws + off);   off += al256((size_t)NN * HH * 4);
    float*  gsum   = (float*)(ws + off);  off += (size_t)GG * HH * 4;
    int*    gcnt   = (int*)(ws + off);    off += al256((size_t)GG * 4);

    // metaS (coarse-sorted packed edges, 6.4MB) and tB (bf16 t-buffer, 25.6MB)
    // both overlay bufB: metaS fully consumed by k_fine before first t write.
    int* metaS = (int*)bufB;
    ushort_t* tB = (ushort_t*)bufB;
    ushort_t* hB = (ushort_t*)bufA;       // bf16 h buffer (layer-2/3 outputs)

    hipMemsetAsync(gsum, 0, (size_t)GG * HH * 4, stream);

    // weight fragment prep + per-graph counts (merged, one launch)
    k_wprep<<<17, 256, 0, stream>>>(W2, W3, w2f, w3f, batch, gcnt);

    // atomic-free counting sort -> CSR (+ dinv fused into k_fine)
    k_hist<<<NB, 256, 0, stream>>>(ei, histG);
    k_bscan<<<CB, NB, 0, stream>>>(histG, total);
    k_cbase<<<1, 1024, 0, stream>>>(total, cbase);
    k_cscatter<<<NB, 256, 0, stream>>>(ei, histG, cbase, metaS);
    k_fine<<<CB, 256, 0, stream>>>(metaS, cbase, cnt, offs, col, dinv);

    // layer 1 aggregate in input space (3-dim) + materialize edge weights
    k_aggx<<<NN / 16, 256, 0, stream>>>(x, offs, cnt, col, dinv, wgt, agg);

    // fused layer1 + layer2 matmul (MFMA): t2 = relu(bn1(agg@W1)) @ W2
    k_mml1<<<(NN + 63) / 64, 256, 0, stream>>>(agg, W1, b1, bn1g, bn1b, bn1m, bn1v,
                                               w2f, tB);
    k_agg<<<NN / 8, 256, 0, stream>>>(tB, offs, cnt, col, wgt, dinv,
                                      b2, bn2g, bn2b, bn2m, bn2v, hB);

    // layer 3 (MFMA matmul), then aggregate, then pool
    k_mm<<<(NN + 127) / 128, 256, 0, stream>>>(hB, w3f, tB);
    k_agg<<<NN / 8, 256, 0, stream>>>(tB, offs, cnt, col, wgt, dinv,
                                      b3, bn3g, bn3b, bn3m, bn3v, hB);

    // pool + head
    k_pool<<<PBLK, 128, 0, stream>>>(hB, batch, gsum);
    k_head<<<1, 128, 0, stream>>>(gsum, gcnt, linW, linb, out);
}

// Round 13
// 393.601 us; speedup vs baseline: 1.1008x; 1.0222x over previous
//
#include <hip/hip_runtime.h>

#define NN 100000
#define EE 1600000
#define GG 64
#define HH 128
#define BN_EPS 1e-5f

#define CB 782            // coarse buckets = ceil(NN/128), bucket = dst>>7
#define NB 250            // tiles for hist/scatter passes
#define TILE 6400         // EE / NB exactly; 256 threads x EPT edges
#define EPT 25            // TILE / 256

typedef unsigned short ushort_t;
typedef __attribute__((ext_vector_type(8))) short bf16x8;
typedef __attribute__((ext_vector_type(4))) float f32x4;

#define MFMA16 __builtin_amdgcn_mfma_f32_16x16x32_bf16

// fragment block size: 128x128 elements = 16384 ushorts (hi), lo follows at +16384
#define WFRAG_LO 16384

// round-to-nearest-even fp32 -> bf16 (finite values)
static __device__ inline ushort_t f2bf(float f) {
    unsigned u = __float_as_uint(f);
    unsigned r = (u + 0x7FFF + ((u >> 16) & 1)) >> 16;
    return (ushort_t)r;
}
static __device__ inline float bf2f(ushort_t b) {
    return __uint_as_float(((unsigned)b) << 16);
}

// ---------------- graph prep: atomic-free two-level counting sort ----------------
// (r6 chain, with k_cscatter upgraded to block-local LDS sort + coalesced
//  write-out: the old version did 1.6M temporally-scattered 4B global writes —
//  the exact pattern r8 measured at 12x HBM write amplification.)

__global__ __launch_bounds__(256) void k_hist(const int* __restrict__ ei,
                                              int* __restrict__ histG) {
    __shared__ int h[CB];
    int t = threadIdx.x;
    for (int i = t; i < CB; i += 256) h[i] = 0;
    __syncthreads();
    int e0 = blockIdx.x * TILE;
    for (int i = t; i < TILE; i += 256) {
        int d = ei[EE + e0 + i];
        atomicAdd(&h[d >> 7], 1);
    }
    __syncthreads();
    for (int i = t; i < CB; i += 256) histG[blockIdx.x * CB + i] = h[i];
}

__global__ __launch_bounds__(256) void k_bscan(int* __restrict__ histG,
                                               int* __restrict__ total) {
    __shared__ int sh[256];
    int t = threadIdx.x;
    int c = blockIdx.x;
    sh[t] = (t < NB) ? histG[t * CB + c] : 0;
    __syncthreads();
    for (int d = 1; d < 256; d <<= 1) {
        int x = (t >= d) ? sh[t - d] : 0;
        __syncthreads();
        sh[t] += x;
        __syncthreads();
    }
    if (t < NB) histG[t * CB + c] = (t > 0) ? sh[t - 1] : 0;
    if (t == 255) total[c] = sh[255];
}

__global__ __launch_bounds__(1024) void k_cbase(const int* __restrict__ total,
                                                int* __restrict__ cbase) {
    __shared__ int sh[1024];
    int t = threadIdx.x;
    sh[t] = (t < CB) ? total[t] : 0;
    __syncthreads();
    for (int d = 1; d < 1024; d <<= 1) {
        int x = (t >= d) ? sh[t - d] : 0;
        __syncthreads();
        sh[t] += x;
        __syncthreads();
    }
    if (t < CB) cbase[t] = (t > 0) ? sh[t - 1] : 0;
    if (t == CB - 1) cbase[CB] = sh[t];   // == EE
}

// coarse scatter with block-local LDS sort: writes go out in bucket-sorted
// order so each (block,bucket) run (~8 edges) is consecutive global addresses.
// metaS placement identical to the old version (base_l[c] + rank).
__global__ __launch_bounds__(256) void k_cscatter(const int* __restrict__ ei,
                                                  const int* __restrict__ histG,
                                                  const int* __restrict__ cbase,
                                                  int* __restrict__ metaS) {
    __shared__ int base_l[CB];
    __shared__ int cnt_l[1024];    // counts, then in-place exclusive offsets
    __shared__ int part[256];
    __shared__ int srt[TILE];
    __shared__ int ga[TILE];
    int t = threadIdx.x;
    int b = blockIdx.x;
    for (int i = t; i < CB; i += 256)
        base_l[i] = cbase[i] + histG[b * CB + i];
    for (int i = t; i < 1024; i += 256) cnt_l[i] = 0;
    __syncthreads();
    int e0 = b * TILE;
    int cs[EPT], rs[EPT], ps[EPT];
#pragma unroll
    for (int k = 0; k < EPT; k++) {
        int i = t + k * 256;                    // coalesced
        int s = ei[e0 + i];
        int d = ei[EE + e0 + i];
        int c = d >> 7;
        cs[k] = c;
        rs[k] = atomicAdd(&cnt_l[c], 1);
        ps[k] = s | ((d & 127) << 17);
    }
    __syncthreads();
    // exclusive scan of cnt_l[0..1023] (4 per thread + block scan of partials)
    int v0 = cnt_l[t * 4], v1 = cnt_l[t * 4 + 1];
    int v2 = cnt_l[t * 4 + 2], v3 = cnt_l[t * 4 + 3];
    part[t] = v0 + v1 + v2 + v3;
    __syncthreads();
    for (int d = 1; d < 256; d <<= 1) {
        int x = (t >= d) ? part[t - d] : 0;
        __syncthreads();
        part[t] += x;
        __syncthreads();
    }
    int excl = (t > 0) ? part[t - 1] : 0;
    cnt_l[t * 4]     = excl;
    cnt_l[t * 4 + 1] = excl + v0;
    cnt_l[t * 4 + 2] = excl + v0 + v1;
    cnt_l[t * 4 + 3] = excl + v0 + v1 + v2;
    __syncthreads();
    // scatter into LDS sorted order + precompute global addresses
#pragma unroll
    for (int k = 0; k < EPT; k++) {
        int c = cs[k];
        int slot = cnt_l[c] + rs[k];
        srt[slot] = ps[k];
        ga[slot] = base_l[c] + rs[k];
    }
    __syncthreads();
    // write-out in sorted order: consecutive threads -> consecutive addrs per run
#pragma unroll
    for (int k = 0; k < EPT; k++) {
        int i = t + k * 256;
        metaS[ga[i]] = srt[i];
    }
}

// pass D: fine histogram, cnt/offs, sorted col; dinv fused at the end
__global__ __launch_bounds__(256) void k_fine(const int* __restrict__ metaS,
                                              const int* __restrict__ cbase,
                                              int* __restrict__ cnt,
                                              int* __restrict__ offs,
                                              int* __restrict__ col,
                                              float* __restrict__ dinv) {
    __shared__ int hist[128];
    __shared__ int scn[128];
    __shared__ int cur[128];
    int t = threadIdx.x;
    int c = blockIdx.x;
    int lo = cbase[c], hi = cbase[c + 1];
    if (t < 128) hist[t] = 0;
    __syncthreads();
    for (int r = lo + t; r < hi; r += 256) atomicAdd(&hist[metaS[r] >> 17], 1);
    __syncthreads();
    if (t < 128) scn[t] = hist[t];
    __syncthreads();
    for (int d = 1; d < 128; d <<= 1) {
        int x = (t >= d && t < 128) ? scn[t - d] : 0;
        __syncthreads();
        if (t < 128) scn[t] += x;
        __syncthreads();
    }
    if (t < 128) {
        int excl = (t > 0) ? scn[t - 1] : 0;
        cur[t] = excl;
        int node = c * 128 + t;
        if (node < NN) {
            cnt[node] = hist[t];
            offs[node] = lo + excl;
            dinv[node] = rsqrtf((float)(hist[t] + 1));   // +1 self loop
        }
    }
    __syncthreads();
    for (int r = lo + t; r < hi; r += 256) {
        int pk = metaS[r];
        int s = pk & 0x1FFFF;
        int idx = atomicAdd(&cur[pk >> 17], 1);
        col[lo + idx] = s;
    }
}

// ---------------- weight prep + per-graph counts (merged: one launch) ----------------
// blocks 0-15: fp32 W -> hi/lo bf16 MFMA B-fragments
// block 16: binary-search per-graph node counts on sorted batch

__global__ __launch_bounds__(256) void k_wprep(const float* __restrict__ W2,
                                               const float* __restrict__ W3,
                                               ushort_t* __restrict__ w2f,
                                               ushort_t* __restrict__ w3f,
                                               const int* __restrict__ batch,
                                               int* __restrict__ gcnt) {
    if (blockIdx.x == 16) {
        int g = threadIdx.x;
        if (g < 64) {
            int lo = 0, hi = NN;
            while (lo < hi) { int mid = (lo + hi) >> 1; if (batch[mid] < g) lo = mid + 1; else hi = mid; }
            int a = lo;
            lo = 0; hi = NN;
            int g1 = g + 1;
            while (lo < hi) { int mid = (lo + hi) >> 1; if (batch[mid] < g1) lo = mid + 1; else hi = mid; }
            gcnt[g] = lo - a;
        }
        return;
    }
    const float* W = (blockIdx.x & 8) ? W3 : W2;
    ushort_t* o = (blockIdx.x & 8) ? w3f : w2f;
    int tid = ((int)blockIdx.x & 7) * 256 + threadIdx.x;   // 0..2047 = (nt*4+kk)*64 + lane
    int l = tid & 63;
    int kb = ((tid >> 6) & 3) * 32 + (l >> 4) * 8;
    int n = (tid >> 8) * 16 + (l & 15);
    unsigned hp[4], lp[4];
#pragma unroll
    for (int p = 0; p < 4; p++) {
        float v0 = W[(size_t)(kb + 2 * p) * HH + n];
        float v1 = W[(size_t)(kb + 2 * p + 1) * HH + n];
        ushort_t h0 = f2bf(v0), h1 = f2bf(v1);
        ushort_t l0 = f2bf(v0 - bf2f(h0)), l1 = f2bf(v1 - bf2f(h1));
        hp[p] = (unsigned)h0 | ((unsigned)h1 << 16);
        lp[p] = (unsigned)l0 | ((unsigned)l1 << 16);
    }
    *(uint4*)&o[(size_t)tid * 8] = make_uint4(hp[0], hp[1], hp[2], hp[3]);
    *(uint4*)&o[WFRAG_LO + (size_t)tid * 8] = make_uint4(lp[0], lp[1], lp[2], lp[3]);
}

// ---------------- layer 1 aggregate (3-dim) + weight materialize (r6 exact) ----------

__global__ __launch_bounds__(256) void k_aggx(const float* __restrict__ x,
                                              const int* __restrict__ offs,
                                              const int* __restrict__ cnt,
                                              const int* __restrict__ col,
                                              const float* __restrict__ dinv,
                                              float* __restrict__ wgt,
                                              float4* __restrict__ agg) {
    int tid = threadIdx.x;
    int wave = tid >> 6;
    int lane = tid & 63;
    int grp = lane >> 4;
    int l = lane & 15;
    int n = blockIdx.x * 16 + wave * 4 + grp;    // NN % 16 == 0
    float dv = dinv[n];
    int base = offs[n], cn = cnt[n];
    float a0 = 0.f, a1 = 0.f, a2 = 0.f;
    for (int i = l; i < cn; i += 16) {
        int s = col[base + i];
        float w = dinv[s] * dv;
        wgt[base + i] = w;
        a0 += w * x[s * 3 + 0];
        a1 += w * x[s * 3 + 1];
        a2 += w * x[s * 3 + 2];
    }
#pragma unroll
    for (int off = 8; off >= 1; off >>= 1) {
        a0 += __shfl_xor(a0, off, 16);
        a1 += __shfl_xor(a1, off, 16);
        a2 += __shfl_xor(a2, off, 16);
    }
    if (l == 0) {
        float w0 = dv * dv;
        a0 += w0 * x[n * 3 + 0];
        a1 += w0 * x[n * 3 + 1];
        a2 += w0 * x[n * 3 + 2];
        agg[n] = make_float4(a0, a1, a2, 0.f);
    }
}

// ---------------- fused layer1 + layer2: t2 = relu(bn(agg@W1)) @ W2 via MFMA ----------

__global__ __launch_bounds__(256) void k_mml1(const float4* __restrict__ agg,
                                              const float* __restrict__ W1,
                                              const float* __restrict__ b1,
                                              const float* __restrict__ g1,
                                              const float* __restrict__ bb1,
                                              const float* __restrict__ m1,
                                              const float* __restrict__ v1,
                                              const ushort_t* __restrict__ Wf,
                                              ushort_t* __restrict__ outB) {
    __shared__ float4 ag[64];
    __shared__ __align__(16) ushort_t xh[2][64 * HH];
    int tid = threadIdx.x;
    int row0 = blockIdx.x * 64;
    if (tid < 64) {
        int gr = row0 + tid;
        ag[tid] = (gr < NN) ? agg[gr] : make_float4(0.f, 0.f, 0.f, 0.f);
    }
    __syncthreads();
    {
        int c = tid & 127;
        int rh = tid >> 7;
        float w0 = W1[c], w1 = W1[128 + c], w2 = W1[256 + c];
        float sc = g1[c] * rsqrtf(v1[c] + BN_EPS);
        float sh = (b1[c] - m1[c]) * sc + bb1[c];
#pragma unroll
        for (int i = 0; i < 32; i++) {
            int r = 2 * i + rh;
            float4 a = ag[r];
            float t = fmaxf((a.x * w0 + a.y * w1 + a.z * w2) * sc + sh, 0.f);
            ushort_t hi = f2bf(t);
            ushort_t lo = f2bf(t - bf2f(hi));
            int idx = r * HH + (c ^ ((r & 7) << 3));   // XOR swizzle, granule=8 elems
            xh[0][idx] = hi;
            xh[1][idx] = lo;
        }
    }
    __syncthreads();

    int w = tid >> 6, l = tid & 63;
    int r_lo = l & 15, kgrp = l >> 4;
    int row_l = w * 16 + r_lo;                 // local A row 0..63
    f32x4 acc[8];
#pragma unroll
    for (int nt = 0; nt < 8; nt++) acc[nt] = (f32x4){0.f, 0.f, 0.f, 0.f};

#pragma unroll
    for (int kk = 0; kk < 4; kk++) {
        int ke = kk * 32 + kgrp * 8;
        int idx = row_l * HH + (ke ^ ((row_l & 7) << 3));
        bf16x8 ahf = *(const bf16x8*)&xh[0][idx];
        bf16x8 alf = *(const bf16x8*)&xh[1][idx];
#pragma unroll
        for (int nt = 0; nt < 8; nt++) {
            int fo = ((((nt << 2) | kk) << 6) + l) * 8;
            bf16x8 bh = *(const bf16x8*)&Wf[fo];
            bf16x8 bl = *(const bf16x8*)&Wf[WFRAG_LO + fo];
            acc[nt] = MFMA16(ahf, bh, acc[nt], 0, 0, 0);
            acc[nt] = MFMA16(ahf, bl, acc[nt], 0, 0, 0);
            acc[nt] = MFMA16(alf, bh, acc[nt], 0, 0, 0);
        }
    }
    // D layout: col = nt*16 + (lane&15), row = (lane>>4)*4 + q
#pragma unroll
    for (int q = 0; q < 4; q++) {
        int gr = row0 + w * 16 + kgrp * 4 + q;
        if (gr < NN) {
            size_t rb = (size_t)gr * HH + r_lo;
#pragma unroll
            for (int nt = 0; nt < 8; nt++)
                outB[rb + nt * 16] = f2bf(acc[nt][q]);
        }
    }
}

// ---------------- dense 128x128 matmul via MFMA, bf16 in / bf16 out ----------------

__global__ __launch_bounds__(256) void k_mm(const ushort_t* __restrict__ xin,
                                            const ushort_t* __restrict__ Wf,
                                            ushort_t* __restrict__ outB) {
    int tid = threadIdx.x;
    int w = tid >> 6, l = tid & 63;
    int row0 = blockIdx.x * 128 + w * 32;
    int r_lo = l & 15, kgrp = l >> 4;
    f32x4 acc[2][8];
#pragma unroll
    for (int rt = 0; rt < 2; rt++)
#pragma unroll
        for (int nt = 0; nt < 8; nt++) acc[rt][nt] = (f32x4){0.f, 0.f, 0.f, 0.f};

    bf16x8 za = {0, 0, 0, 0, 0, 0, 0, 0};
#pragma unroll
    for (int kk = 0; kk < 4; kk++) {
        int ke = kk * 32 + kgrp * 8;
        int ra0 = row0 + r_lo;
        int ra1 = row0 + 16 + r_lo;
        bf16x8 a0 = (ra0 < NN) ? *(const bf16x8*)&xin[(size_t)ra0 * HH + ke] : za;
        bf16x8 a1 = (ra1 < NN) ? *(const bf16x8*)&xin[(size_t)ra1 * HH + ke] : za;
#pragma unroll
        for (int nt = 0; nt < 8; nt++) {
            int fo = ((((nt << 2) | kk) << 6) + l) * 8;
            bf16x8 bh = *(const bf16x8*)&Wf[fo];
            bf16x8 bl = *(const bf16x8*)&Wf[WFRAG_LO + fo];
            acc[0][nt] = MFMA16(a0, bh, acc[0][nt], 0, 0, 0);
            acc[0][nt] = MFMA16(a0, bl, acc[0][nt], 0, 0, 0);
            acc[1][nt] = MFMA16(a1, bh, acc[1][nt], 0, 0, 0);
            acc[1][nt] = MFMA16(a1, bl, acc[1][nt], 0, 0, 0);
        }
    }
#pragma unroll
    for (int rt = 0; rt < 2; rt++)
#pragma unroll
        for (int q = 0; q < 4; q++) {
            int gr = row0 + rt * 16 + kgrp * 4 + q;
            if (gr < NN) {
                size_t rb = (size_t)gr * HH + r_lo;
#pragma unroll
                for (int nt = 0; nt < 8; nt++)
                    outB[rb + nt * 16] = f2bf(acc[rt][nt][q]);
            }
        }
}

// ---------------- gather-aggregate, FROZEN r0 structure (76us floor) ------
// Structural limit established r7/r10/r11: bound by L2-miss fill traffic for
// random 256B rows; insensitive to MLP (r7), load count (r10), and working-set
// size (r11). Do not restructure.

__global__ __launch_bounds__(256) void k_agg(const ushort_t* __restrict__ t,
                                             const int* __restrict__ offs,
                                             const int* __restrict__ cnt,
                                             const int* __restrict__ col,
                                             const float* __restrict__ wgt,
                                             const float* __restrict__ dinv,
                                             const float* __restrict__ bias,
                                             const float* __restrict__ g,
                                             const float* __restrict__ bb,
                                             const float* __restrict__ m,
                                             const float* __restrict__ v,
                                             ushort_t* __restrict__ out) {
    int wave = threadIdx.x >> 6;
    int lane = threadIdx.x & 63;
    int half = lane >> 5;
    int l = lane & 31;
    int d = blockIdx.x * 8 + wave * 2 + half;    // NN % 8 == 0
    int c0 = l * 4;
    float dv = dinv[d];
    float w0 = dv * dv;
    ushort4 selfR = *(const ushort4*)&t[(size_t)d * HH + c0];
    float4 acc;
    acc.x = bf2f(selfR.x) * w0; acc.y = bf2f(selfR.y) * w0;
    acc.z = bf2f(selfR.z) * w0; acc.w = bf2f(selfR.w) * w0;
    int base = offs[d], cn = cnt[d];
    for (int ib = 0; ib < cn; ib += 32) {
        int i = ib + l;
        int s = 0;
        float w = 0.f;
        if (i < cn) {
            s = col[base + i];
            w = wgt[base + i];
        }
        int lim = min(32, cn - ib);
#pragma unroll 8
        for (int j = 0; j < lim; j++) {
            int ss = __shfl(s, j, 32);
            float ww = __shfl(w, j, 32);
            ushort4 tv = *(const ushort4*)&t[(size_t)ss * HH + c0];
            acc.x += ww * bf2f(tv.x);
            acc.y += ww * bf2f(tv.y);
            acc.z += ww * bf2f(tv.z);
            acc.w += ww * bf2f(tv.w);
        }
    }
    float4 gg = *(const float4*)&g[c0];
    float4 vv = *(const float4*)&v[c0];
    float4 mm = *(const float4*)&m[c0];
    float4 bv = *(const float4*)&bb[c0];
    float4 bi = *(const float4*)&bias[c0];
    float sc0 = gg.x * rsqrtf(vv.x + BN_EPS);
    float sc1 = gg.y * rsqrtf(vv.y + BN_EPS);
    float sc2 = gg.z * rsqrtf(vv.z + BN_EPS);
    float sc3 = gg.w * rsqrtf(vv.w + BN_EPS);
    ushort4 o;
    o.x = f2bf(fmaxf(acc.x * sc0 + (bi.x - mm.x) * sc0 + bv.x, 0.f));
    o.y = f2bf(fmaxf(acc.y * sc1 + (bi.y - mm.y) * sc1 + bv.y, 0.f));
    o.z = f2bf(fmaxf(acc.z * sc2 + (bi.z - mm.z) * sc2 + bv.z, 0.f));
    o.w = f2bf(fmaxf(acc.w * sc3 + (bi.w - mm.w) * sc3 + bv.w, 0.f));
    *(ushort4*)&out[(size_t)d * HH + c0] = o;
}

// ---------------- mean pool (bf16 in, fp32 accum) — exact 32-node chunks ----------------

#define PBLK 3125            // 3125 * 32 == NN exactly
__global__ void k_pool(const ushort_t* __restrict__ h, const int* __restrict__ batch,
                       float* __restrict__ gsum) {
    int c = threadIdx.x;  // 128
    int n0 = blockIdx.x * 32;
    int n1 = n0 + 32;
    float acc = 0.f;
    int cur = batch[n0];
    for (int n = n0; n < n1; n++) {
        int gr = batch[n];
        if (gr != cur) {
            atomicAdd(&gsum[cur * HH + c], acc);
            acc = 0.f; cur = gr;
        }
        acc += bf2f(h[(size_t)n * HH + c]);
    }
    atomicAdd(&gsum[cur * HH + c], acc);
}

// ---------------- head ----------------

__global__ void k_head(const float* __restrict__ gsum, const int* __restrict__ gcnt,
                       const float* __restrict__ linW, const float* __restrict__ linb,
                       float* __restrict__ out) {
    int t = threadIdx.x;        // 128 = 64 graphs x 2 outputs
    int gr = t >> 1, j = t & 1;
    float inv = 1.0f / fmaxf((float)gcnt[gr], 1.0f);
    float acc = 0.f;
    for (int c = 0; c < HH; c++) acc += gsum[gr * HH + c] * linW[c * 2 + j];
    out[t] = acc * inv + linb[j];
}

// ---------------- host launch ----------------

static inline size_t al256(size_t x) { return (x + 255) & ~(size_t)255; }

extern "C" void kernel_launch(void* const* d_in, const int* in_sizes, int n_in,
                              void* d_out, int out_size, void* d_ws, size_t ws_size,
                              hipStream_t stream) {
    const float* x    = (const float*)d_in[0];
    const int*   ei   = (const int*)d_in[1];
    const int*   batch= (const int*)d_in[2];
    const float* W1   = (const float*)d_in[3];
    const float* b1   = (const float*)d_in[4];
    const float* W2   = (const float*)d_in[5];
    const float* b2   = (const float*)d_in[6];
    const float* W3   = (const float*)d_in[7];
    const float* b3   = (const float*)d_in[8];
    const float* linW = (const float*)d_in[9];
    const float* linb = (const float*)d_in[10];
    const float* bn1g = (const float*)d_in[11];
    const float* bn1b = (const float*)d_in[12];
    const float* bn1m = (const float*)d_in[13];
    const float* bn1v = (const float*)d_in[14];
    const float* bn2g = (const float*)d_in[15];
    const float* bn2b = (const float*)d_in[16];
    const float* bn2m = (const float*)d_in[17];
    const float* bn2v = (const float*)d_in[18];
    const float* bn3g = (const float*)d_in[19];
    const float* bn3b = (const float*)d_in[20];
    const float* bn3m = (const float*)d_in[21];
    const float* bn3v = (const float*)d_in[22];
    float* out = (float*)d_out;

    char* ws = (char*)d_ws;
    size_t off = 0;
    int*    histG  = (int*)(ws + off);    off += al256((size_t)NB * CB * 4);
    int*    total  = (int*)(ws + off);    off += al256((size_t)CB * 4);
    int*    cbase  = (int*)(ws + off);    off += al256((size_t)(CB + 1) * 4);
    int*    cnt    = (int*)(ws + off);    off += al256((size_t)NN * 4);
    int*    offs   = (int*)(ws + off);    off += al256((size_t)NN * 4);
    float*  dinv   = (float*)(ws + off);  off += al256((size_t)NN * 4);
    int*    col    = (int*)(ws + off);    off += al256((size_t)EE * 4);
    float*  wgt    = (float*)(ws + off);  off += al256((size_t)EE * 4);
    ushort_t* w2f  = (ushort_t*)(ws + off); off += al256((size_t)2 * WFRAG_LO * 2);
    ushort_t* w3f  = (ushort_t*)(ws + off); off += al256((size_t)2 * WFRAG_LO * 2);
    float4* agg    = (float4*)(ws + off); off += al256((size_t)NN * 16);
    char*   bufA   = (char*)(ws + off);   off += al256((size_t)NN * HH * 2);
    char*   bufB   = (char*)(ws + off);   off += al256((size_t)NN * HH * 4);
    float*  gsum   = (float*)(ws + off);  off += (size_t)GG * HH * 4;
    int*    gcnt   = (int*)(ws + off);    off += al256((size_t)GG * 4);

    // metaS (coarse-sorted packed edges, 6.4MB) and tB (bf16 t-buffer, 25.6MB)
    // both overlay bufB: metaS fully consumed by k_fine before first t write.
    int* metaS = (int*)bufB;
    ushort_t* tB = (ushort_t*)bufB;
    ushort_t* hB = (ushort_t*)bufA;       // bf16 h buffer (layer-2/3 outputs)

    hipMemsetAsync(gsum, 0, (size_t)GG * HH * 4, stream);

    // weight fragment prep + per-graph counts (merged, one launch)
    k_wprep<<<17, 256, 0, stream>>>(W2, W3, w2f, w3f, batch, gcnt);

    // atomic-free counting sort -> CSR (+ dinv fused into k_fine)
    k_hist<<<NB, 256, 0, stream>>>(ei, histG);
    k_bscan<<<CB, 256, 0, stream>>>(histG, total);
    k_cbase<<<1, 1024, 0, stream>>>(total, cbase);
    k_cscatter<<<NB, 256, 0, stream>>>(ei, histG, cbase, metaS);
    k_fine<<<CB, 256, 0, stream>>>(metaS, cbase, cnt, offs, col, dinv);

    // layer 1 aggregate in input space (3-dim) + materialize edge weights
    k_aggx<<<NN / 16, 256, 0, stream>>>(x, offs, cnt, col, dinv, wgt, agg);

    // fused layer1 + layer2 matmul (MFMA): t2 = relu(bn1(agg@W1)) @ W2
    k_mml1<<<(NN + 63) / 64, 256, 0, stream>>>(agg, W1, b1, bn1g, bn1b, bn1m, bn1v,
                                               w2f, tB);
    k_agg<<<NN / 8, 256, 0, stream>>>(tB, offs, cnt, col, wgt, dinv,
                                      b2, bn2g, bn2b, bn2m, bn2v, hB);

    // layer 3 (MFMA matmul), then aggregate, then pool
    k_mm<<<(NN + 127) / 128, 256, 0, stream>>>(hB, w3f, tB);
    k_agg<<<NN / 8, 256, 0, stream>>>(tB, offs, cnt, col, wgt, dinv,
                                      b3, bn3g, bn3b, bn3m, bn3v, hB);

    // pool + head
    k_pool<<<PBLK, 128, 0, stream>>>(hB, batch, gsum);
    k_head<<<1, 128, 0, stream>>>(gsum, gcnt, linW, linb, out);
}